// Round 8
// baseline (548.441 us; speedup 1.0000x reference)
//
#include <hip/hip_runtime.h>
#include <math.h>

typedef unsigned short u16;
typedef unsigned int   u32;
using f32x4  = __attribute__((ext_vector_type(4))) float;
using bf16x8 = __attribute__((ext_vector_type(8))) __bf16;

#define HIDDEN   2880
#define QKVD     5120
#define QD       4096
#define TTOK     2048
#define NKV      8
#define QMULT    8
#define HD       64
#define NPAD     2944   // w_out rows padded to 23*128 (GEMM2 store-guards col<2944)

#define PREP_QKV_BLOCKS  14400   // QKVD*HIDDEN/4/256
#define PREP_RMS_BLOCKS  2048

static __device__ __forceinline__ float bflo(u32 u){ return __uint_as_float(u << 16); }
static __device__ __forceinline__ float bfhi(u32 u){ return __uint_as_float(u & 0xffff0000u); }
static __device__ __forceinline__ u16 f2bf(float f){
    u32 u = __float_as_uint(f);
    u32 r = (u + 0x7fffu + ((u >> 16) & 1u)) >> 16;
    return (u16)r;
}

static __device__ __forceinline__ void glds16(const void* g, void* l) {
    __builtin_amdgcn_global_load_lds(
        (__attribute__((address_space(1))) void*)g,
        (__attribute__((address_space(3))) void*)l,
        16, 0, 0);
}

// ---------------- fused prep: w_qkv cvt | rmsnorm ----------------
__global__ __launch_bounds__(256) void prep_kernel(const float* __restrict__ w_qkv,
                                                   u16* __restrict__ wqkv_bf,
                                                   const float* __restrict__ x,
                                                   const float* __restrict__ scale,
                                                   u16* __restrict__ h) {
    const int b = blockIdx.x;
    const int tid = threadIdx.x;
    if (b < PREP_QKV_BLOCKS) {
        int i = b * 256 + tid;
        float4 f = ((const float4*)w_qkv)[i];
        ushort4 o;
        o.x = f2bf(f.x); o.y = f2bf(f.y); o.z = f2bf(f.z); o.w = f2bf(f.w);
        ((ushort4*)wqkv_bf)[i] = o;
    } else {
        const int t = b - PREP_QKV_BLOCKS;
        const float4* xr = (const float4*)(x + (long)t * HIDDEN);
        float4 v[3];
        float ss = 0.f;
        #pragma unroll
        for (int it = 0; it < 3; ++it) {
            int i4 = tid + it * 256;
            if (i4 < 720) {
                v[it] = xr[i4];
                ss += v[it].x*v[it].x + v[it].y*v[it].y + v[it].z*v[it].z + v[it].w*v[it].w;
            }
        }
        #pragma unroll
        for (int off = 32; off > 0; off >>= 1) ss += __shfl_down(ss, off);
        __shared__ float red[4];
        if ((tid & 63) == 0) red[tid >> 6] = ss;
        __syncthreads();
        float tot = red[0] + red[1] + red[2] + red[3];
        float rr = rsqrtf(tot * (1.0f / HIDDEN) + 1e-5f);
        ushort4* hr = (ushort4*)(h + (long)t * HIDDEN);
        #pragma unroll
        for (int it = 0; it < 3; ++it) {
            int i4 = tid + it * 256;
            if (i4 < 720) {
                float4 s4 = ((const float4*)scale)[i4];
                ushort4 o;
                o.x = f2bf(v[it].x * rr * s4.x);
                o.y = f2bf(v[it].y * rr * s4.y);
                o.z = f2bf(v[it].z * rr * s4.z);
                o.w = f2bf(v[it].w * rr * s4.w);
                hr[i4] = o;
            }
        }
    }
}

// ---- R8: occupancy GEMM, corrected. 128x256 / BK=32 / 4 waves / 64x128 wave tile
// R7 post-mortem: (a) swizzle chunk^=(row&3) put lanes 0-7 on only 4 of 8
// bank-quads (2 each) -> 7.37M conflicts; (b) 64x64 wave tiles read 0.5 b128/MFMA
// (vs 0.375 for 64x128) -> LDS-pipe-bound. This round:
//  - wave tile 64x128 (4 waves: wm2=wv>>1 M-half, wn2=wv&1 N-half), BK=32:
//    12 b128 reads / 32 MFMA per wave-tile step = 0.375 ratio.
//  - LDS 48KB static (A[2][128][32] 16K + B[2][256][32] 32K) -> 3 blocks/CU;
//    regs ~205 < 682 @ 3 waves/SIMD. Cross-block overlap hides the per-block
//    __syncthreads drain (m97/m114 mechanism).
//  - Swizzle for 64B rows (derived, per-8-lane-group quad-exact): read chunk =
//    (lane>>4) ^ ((lane>>1)&3); staging source chunk = (tid&3) ^ ((row>>1)&3).
//    Enumeration: lanes 0-7 -> quads 0,4,1,5,2,6,3,7 (all distinct); same for
//    every 8-lane group. Both-sides involution (rule #21).
__global__ __launch_bounds__(256, 3) void gemm_bt(const u16* __restrict__ A,
                                                  const u16* __restrict__ B,
                                                  u16* __restrict__ C0,
                                                  int N, int K, int ksplit,
                                                  int blimit, int colmax,
                                                  int nz_gemm,
                                                  const float* __restrict__ wout_src,
                                                  u16* __restrict__ wout_dst) {
    const int tid  = threadIdx.x;

    if ((int)blockIdx.z >= nz_gemm) {
        // ---- filler blocks: w_out cvt+pad [HIDDEN][QD] f32 -> [NPAD][QD] bf16 ----
        const long nb = (long)gridDim.x * gridDim.y;
        long bidx = (long)blockIdx.y * gridDim.x + blockIdx.x;
        long i = bidx * 256 + tid;
        const long tot = (long)NPAD * QD / 4;
        const long stride = nb * 256;
        for (; i < tot; i += stride) {
            long idx = i * 4;
            int row = (int)(idx >> 12);
            int col = (int)(idx & 4095);
            ushort4 o;
            if (row < HIDDEN) {
                float4 f = *(const float4*)(wout_src + (long)row * QD + col);
                o.x = f2bf(f.x); o.y = f2bf(f.y); o.z = f2bf(f.z); o.w = f2bf(f.w);
            } else {
                o.x = 0; o.y = 0; o.z = 0; o.w = 0;
            }
            ((ushort4*)wout_dst)[i] = o;
        }
        return;
    }

    __shared__ __align__(16) u16 smA[2][128 * 32];   // 8 KB per slot
    __shared__ __align__(16) u16 smB[2][256 * 32];   // 16 KB per slot
    const int lane = tid & 63;
    const int wv   = tid >> 6;              // wave 0..3
    const int wm2  = wv >> 1;               // 0..1 (M half, 64 rows)
    const int wn2  = wv & 1;                // 0..1 (N half, 128 cols)
    const long m0  = (long)blockIdx.y * 128;
    const long n0  = (long)blockIdx.x * 256;
    const int kbase = blockIdx.z * ksplit;
    int krem = K - kbase; if (krem > ksplit) krem = ksplit;
    const int NT   = krem >> 5;             // K-tiles of 32
    u16* C = C0 + (size_t)blockIdx.z * ((size_t)TTOK * N);

    // staging: thread covers rows (tid>>2)+p*64, 16B chunk tid&3; source chunk
    // pre-swizzled with (row>>1)&3 == (tid>>3)&3 (p*64 contributes 0 mod 4)
    const int sg8  = ((tid & 3) ^ ((tid >> 3) & 3)) << 3;   // element offset
    // fragment reads: chunk = (lane>>4) ^ ((fr>>1)&3); bits1-2 of lane == of fr
    const int fr   = lane & 15;
    const int offr = (((lane >> 4) ^ ((lane >> 1) & 3)) << 4);
    const char* aBase = (const char*)smA + (wm2 * 64  + fr) * 64 + offr;
    const char* bBase = (const char*)smB + (wn2 * 128 + fr) * 64 + offr;

    f32x4 acc[4][8];
    #pragma unroll
    for (int i = 0; i < 4; ++i)
        #pragma unroll
        for (int j = 0; j < 8; ++j) acc[i][j] = f32x4{0.f, 0.f, 0.f, 0.f};

    const int srow = tid >> 2;   // 0..63
    auto stage = [&](int t, int buf) {
        // A: 128 rows x 64B in 2 passes (wave-uniform dest; HW adds lane*16)
        #pragma unroll
        for (int p = 0; p < 2; ++p) {
            long r = m0 + srow + p * 64;
            glds16(A + (size_t)r * K + kbase + t * 32 + sg8,
                   (char*)smA + buf * 8192 + p * 4096 + wv * 1024);
        }
        // B: 256 rows in 4 passes
        #pragma unroll
        for (int p = 0; p < 4; ++p) {
            long r = n0 + srow + p * 64;
            if (r > blimit) r = blimit;   // clamp into zero-padded rows
            glds16(B + (size_t)r * K + kbase + t * 32 + sg8,
                   (char*)smB + buf * 16384 + p * 4096 + wv * 1024);
        }
    };

    stage(0, 0);
    int ib = 0;
    for (int t = 0; t < NT; ++t, ib ^= 1) {
        __syncthreads();                 // drains stage(t); protects buf ib^1
        if (t + 1 < NT) stage(t + 1, ib ^ 1);
        bf16x8 aq[4], bq[8];
        #pragma unroll
        for (int mi = 0; mi < 4; ++mi)
            aq[mi] = *(const bf16x8*)(aBase + ib * 8192 + mi * 1024);
        #pragma unroll
        for (int nf = 0; nf < 8; ++nf)
            bq[nf] = *(const bf16x8*)(bBase + ib * 16384 + nf * 1024);
        #pragma unroll
        for (int mi = 0; mi < 4; ++mi)
            #pragma unroll
            for (int nf = 0; nf < 8; ++nf)
                acc[mi][nf] = __builtin_amdgcn_mfma_f32_16x16x32_bf16(aq[mi], bq[nf], acc[mi][nf], 0, 0, 0);
    }

    // epilogue: C/D layout col=lane&15, row=(lane>>4)*4+reg  [m89-verified]
    const int cr = (lane >> 4) * 4;
    const int cc = lane & 15;
    #pragma unroll
    for (int nf = 0; nf < 8; ++nf) {
        long col = n0 + wn2 * 128 + nf * 16 + cc;
        if (col < colmax) {
            #pragma unroll
            for (int mi = 0; mi < 4; ++mi) {
                long row = m0 + wm2 * 64 + mi * 16 + cr;
                #pragma unroll
                for (int r2 = 0; r2 < 4; ++r2)
                    C[(row + r2) * (long)N + col] = f2bf(acc[mi][nf][r2]);
            }
        }
    }
}

// ------- RoPE (YaRN), consumes nsplit GEMM1 split-K partials + bias -------------
__global__ __launch_bounds__(256) void rope_kernel(const u16* __restrict__ p1,
                                                   const float* __restrict__ b_qkv,
                                                   u16* __restrict__ qr,
                                                   u16* __restrict__ kr,
                                                   u16* __restrict__ vr,
                                                   int nsplit) {
    const int t = blockIdx.x;
    const int tid = threadIdx.x;
    __shared__ float cs[32], sn[32];
    if (tid < 32) {
        float fi = (float)tid;
        float freq   = exp2f(17.1946032f * (fi * (1.0f / 32.0f)));   // 150000^(i/32)
        float interp = 1.0f / (32.0f * freq);
        float extra  = 1.0f / freq;
        float ramp   = (fi - 8.0927802f) * (1.0f / (17.3980220f - 8.0927802f));
        float rc     = fminf(fmaxf(ramp, 0.0f), 1.0f);               // = 1 - mask
        float invf   = interp * rc + extra * (1.0f - rc);
        float ang    = (float)t * invf;
        cs[tid] = cosf(ang) * 1.3465736f;                            // * concentration
        sn[tid] = sinf(ang) * 1.3465736f;
    }
    __syncthreads();
    const u16* rowA = p1 + (long)t * QKVD;
    auto pair = [&](int col) -> float2 {
        float2 bb = *(const float2*)(b_qkv + col);
        float a = bb.x, b = bb.y;
        for (int s = 0; s < nsplit; ++s) {
            u32 u = *(const u32*)(rowA + (size_t)s * TTOK * QKVD + col);
            a += bflo(u); b += bfhi(u);
        }
        return make_float2(a, b);
    };
    // Q: 64 heads x 32 pairs
    for (int p = tid; p < 2048; p += 256) {
        int hd2 = p >> 5, i = p & 31;
        float2 ab = pair(hd2 * 64 + 2 * i);
        float o1 = ab.x * cs[i] - ab.y * sn[i];
        float o2 = ab.y * cs[i] + ab.x * sn[i];
        *(u32*)(qr + (long)t * QD + hd2 * 64 + 2 * i) = (u32)f2bf(o1) | ((u32)f2bf(o2) << 16);
    }
    // K: 8 heads x 32 pairs == 256 threads; head-major layout [kv][t][64]
    {
        int kv = tid >> 5, i = tid & 31;
        float2 ab = pair(QD + kv * 64 + 2 * i);
        float o1 = ab.x * cs[i] - ab.y * sn[i];
        float o2 = ab.y * cs[i] + ab.x * sn[i];
        *(u32*)(kr + ((long)kv * TTOK + t) * HD + 2 * i) = (u32)f2bf(o1) | ((u32)f2bf(o2) << 16);
    }
    // V: 8 heads x 64 = 256 u32; head-major [kv][t][64]
    {
        int kv = tid >> 5, d2 = tid & 31;
        float2 ab = pair(QD + 512 + kv * 64 + 2 * d2);
        *(u32*)(vr + ((long)kv * TTOK + t) * HD + 2 * d2) = (u32)f2bf(ab.x) | ((u32)f2bf(ab.y) << 16);
    }
}

// ---------------- MFMA sliding-window attention with sink ----------------
__global__ __launch_bounds__(256, 2) void attn_kernel(const u16* __restrict__ qr,
                                                      const u16* __restrict__ kr,
                                                      const u16* __restrict__ vr,
                                                      const float* __restrict__ sinks,
                                                      u16* __restrict__ o) {
    const int t0  = blockIdx.x * 16;
    const int h   = blockIdx.y;
    const int qhg = blockIdx.z;
    const int tid = threadIdx.x;
    const int lane = tid & 63, wv = tid >> 6;
    __shared__ __align__(16) u16 ks[144][72];    // K rows [key][64+pad]
    __shared__ __align__(16) u16 Vt[64][168];    // V^T [d][key], cols 144..159 zero
    __shared__ __align__(16) u16 P [4][16][168]; // per-wave P [token][key], cols 144..159 zero
    const u16* kb = kr + (long)h * TTOK * HD;
    const u16* vb = vr + (long)h * TTOK * HD;

    // stage K rows (coalesced)
    #pragma unroll
    for (int i = 0; i < 5; ++i) {
        int idx = i * 256 + tid;
        if (idx < 144 * 8) {
            int rr = idx >> 3, c = idx & 7;
            int tk = t0 - 128 + rr;
            int tks = tk < 0 ? 0 : tk;          // clamped; masked later
            *(uint4*)&ks[rr][c * 8] = *(const uint4*)(kb + (long)tks * HD + c * 8);
        }
    }
    // stage V transposed: thread -> one key, 8 dims per pass
    #pragma unroll
    for (int c4 = 0; c4 < 8; ++c4) {
        if (tid < 144) {
            int tk = t0 - 128 + tid;
            int tks = tk < 0 ? 0 : tk;
            uint4 v4 = *(const uint4*)(vb + (long)tks * HD + c4 * 8);
            int d0 = c4 * 8;
            Vt[d0+0][tid] = (u16)(v4.x & 0xffff); Vt[d0+1][tid] = (u16)(v4.x >> 16);
            Vt[d0+2][tid] = (u16)(v4.y & 0xffff); Vt[d0+3][tid] = (u16)(v4.y >> 16);
            Vt[d0+4][tid] = (u16)(v4.z & 0xffff); Vt[d0+5][tid] = (u16)(v4.z >> 16);
            Vt[d0+6][tid] = (u16)(v4.w & 0xffff); Vt[d0+7][tid] = (u16)(v4.w >> 16);
        }
    }
    if (tid < 128) {
        *(uint4*)&Vt[tid >> 1][144 + (tid & 1) * 8] = uint4{0, 0, 0, 0};
    }
    if (lane < 32) {
        *(uint4*)&P[wv][lane >> 1][144 + (lane & 1) * 8] = uint4{0, 0, 0, 0};
    }
    __syncthreads();

    const int qh   = qhg * 4 + wv;
    const int head = h * QMULT + qh;
    const int fr = lane & 15, fk = (lane >> 4) * 8;
    const int cr = (lane >> 4) * 4;

    const u16* qrow = qr + (long)(t0 + fr) * QD + head * HD;
    bf16x8 qf0 = *(const bf16x8*)(qrow + fk);
    bf16x8 qf1 = *(const bf16x8*)(qrow + 32 + fk);

    const int kmin = 128 - t0;          // kk >= kmin <=> key token >= 0
    float lsum[4] = {0.f, 0.f, 0.f, 0.f};

    for (int nt = 0; nt < 9; ++nt) {
        bf16x8 b0 = *(const bf16x8*)&ks[nt * 16 + fr][fk];
        bf16x8 b1 = *(const bf16x8*)&ks[nt * 16 + fr][32 + fk];
        f32x4 s = f32x4{0.f, 0.f, 0.f, 0.f};
        s = __builtin_amdgcn_mfma_f32_16x16x32_bf16(qf0, b0, s, 0, 0, 0);
        s = __builtin_amdgcn_mfma_f32_16x16x32_bf16(qf1, b1, s, 0, 0, 0);
        const int kk = nt * 16 + fr;    // C-layout col = lane&15
        #pragma unroll
        for (int r = 0; r < 4; ++r) {
            int row = cr + r;           // token index within tile
            bool valid = (kk >= row) && (kk <= row + 128) && (kk >= kmin);
            float p = valid ? __expf(s[r] * 0.125f) : 0.0f;
            lsum[r] += p;
            P[wv][row][kk] = f2bf(p);
        }
    }

    f32x4 oacc[4];
    #pragma unroll
    for (int dt = 0; dt < 4; ++dt) oacc[dt] = f32x4{0.f, 0.f, 0.f, 0.f};
    #pragma unroll
    for (int k5 = 0; k5 < 5; ++k5) {
        const int k0 = k5 * 32;
        bf16x8 pa = *(const bf16x8*)&P[wv][fr][k0 + fk];
        #pragma unroll
        for (int dt = 0; dt < 4; ++dt) {
            bf16x8 vf = *(const bf16x8*)&Vt[dt * 16 + fr][k0 + fk];
            oacc[dt] = __builtin_amdgcn_mfma_f32_16x16x32_bf16(pa, vf, oacc[dt], 0, 0, 0);
        }
    }

    #pragma unroll
    for (int r = 0; r < 4; ++r) {
        float v = lsum[r];
        v += __shfl_xor(v, 1);
        v += __shfl_xor(v, 2);
        v += __shfl_xor(v, 4);
        v += __shfl_xor(v, 8);
        lsum[r] = v;
    }
    const float sk = exp2f(sinks[head]);
    float inv[4];
    #pragma unroll
    for (int r = 0; r < 4; ++r) inv[r] = 1.0f / (lsum[r] + sk);

    #pragma unroll
    for (int dt = 0; dt < 4; ++dt) {
        #pragma unroll
        for (int r = 0; r < 4; ++r) {
            o[(long)(t0 + cr + r) * QD + head * HD + dt * 16 + fr] = f2bf(oacc[dt][r] * inv[r]);
        }
    }
}

// ------ reduce GEMM2 nsplit partials + bias + residual -> out -------------------
__global__ __launch_bounds__(256) void reduce2_kernel(const u16* __restrict__ p2,
                                                      const float* __restrict__ x,
                                                      const float* __restrict__ b_out,
                                                      float* __restrict__ out,
                                                      int nsplit) {
    const int row = blockIdx.y;
    const int c4 = blockIdx.x * 256 + threadIdx.x;   // float4 index within row
    if (c4 >= 720) return;
    const int col = c4 * 4;
    float4 xv = *(const float4*)(x + (long)row * HIDDEN + col);
    float4 bv = *(const float4*)(b_out + col);
    float4 o;
    o.x = xv.x + bv.x; o.y = xv.y + bv.y; o.z = xv.z + bv.z; o.w = xv.w + bv.w;
    for (int s = 0; s < nsplit; ++s) {
        ushort4 ua = *(const ushort4*)(p2 + (size_t)s * TTOK * NPAD + (long)row * NPAD + col);
        o.x += __uint_as_float((u32)ua.x << 16);
        o.y += __uint_as_float((u32)ua.y << 16);
        o.z += __uint_as_float((u32)ua.z << 16);
        o.w += __uint_as_float((u32)ua.w << 16);
    }
    *(float4*)(out + (long)row * HIDDEN + col) = o;
}

// ---------------- launcher ----------------
extern "C" void kernel_launch(void* const* d_in, const int* in_sizes, int n_in,
                              void* d_out, int out_size, void* d_ws, size_t ws_size,
                              hipStream_t stream) {
    const float* x      = (const float*)d_in[0];
    const float* nscale = (const float*)d_in[1];
    const float* w_qkv  = (const float*)d_in[2];
    const float* b_qkv  = (const float*)d_in[3];
    const float* sinks  = (const float*)d_in[4];
    const float* w_out  = (const float*)d_in[5];
    const float* b_out  = (const float*)d_in[6];
    float* out = (float*)d_out;

    // GEMM2 split-K ways: 4 -> 768 blocks = exactly 3/CU (balanced); ws-gated.
    const size_t slab2 = (size_t)TTOK * NPAD * 2;              // 12.05 MB / partial
    const size_t fixed = ((size_t)QKVD * HIDDEN * 2)           // wqkv_bf 29.5
                       + ((size_t)NPAD * QD * 2)               // wout_bf 24.1
                       + ((size_t)TTOK * HIDDEN * 2)           // h 11.8
                       + ((size_t)TTOK * QD * 2)               // qrot 16.8
                       + ((size_t)TTOK * QKVD * 2)             // p1 (gemm1 out) 21.0
                       + 8192;
    const int gs2 = (fixed - (size_t)TTOK * QKVD * 2 + 4 * slab2 <= ws_size &&
                     4 * slab2 >= (size_t)TTOK * QKVD * 2) ? 4 : 2;

    char* ws = (char*)d_ws;
    size_t off = 0;
    auto alloc = [&](size_t bytes) { void* p = ws + off; off += (bytes + 255) & ~(size_t)255; return p; };
    const size_t p1_bytes = (size_t)TTOK * QKVD * 2;           // 21.0 MB
    const size_t p2_bytes = (size_t)gs2 * slab2;               // 24.1 or 48.2 MB
    u16* wqkv_bf = (u16*)alloc((size_t)QKVD * HIDDEN * 2);     // 29.5 MB
    u16* wout_bf = (u16*)alloc((size_t)NPAD * QD * 2);         // 24.1 MB
    u16* h       = (u16*)alloc((size_t)TTOK * HIDDEN * 2);     // 11.8 MB
    u16* p1      = (u16*)alloc(p1_bytes > p2_bytes ? p1_bytes : p2_bytes);
    u16* qrot    = (u16*)alloc((size_t)TTOK * QD * 2);         // 16.8 MB
    // aliases (dead-after analysis):
    u16* attn = wqkv_bf;                       // wqkv_bf dead after gemm1 (16.8 MB)
    u16* krot = wqkv_bf + (size_t)TTOK * QD;   // wqkv tail: +2.1 MB
    u16* vrot = krot + (size_t)NKV * TTOK * HD;// +2.1 MB (total 21.0 <= 29.5 OK)
    u16* p2   = p1;                            // p1 dead after rope; sized above

    prep_kernel<<<PREP_QKV_BLOCKS + PREP_RMS_BLOCKS, 256, 0, stream>>>(
        w_qkv, wqkv_bf, x, nscale, h);
    // GEMM1: full-K, 20x16 = 320 gemm blocks (3/CU capacity) + 320 filler blocks
    // (z=1) doing the w_out cvt on spare CU slots
    gemm_bt<<<dim3(QKVD / 256, TTOK / 128, 2), 256, 0, stream>>>(
        h, wqkv_bf, p1, QKVD, HIDDEN, HIDDEN, QKVD - 1, QKVD, 1, w_out, wout_bf);
    rope_kernel<<<TTOK, 256, 0, stream>>>(p1, b_qkv, qrot, krot, vrot, 1);
    attn_kernel<<<dim3(TTOK / 16, NKV, 2), 256, 0, stream>>>(qrot, krot, vrot, sinks, attn);
    // GEMM2: split-K z=gs2 (4 -> 12x16x4 = 768 blocks = exactly 3/CU)
    gemm_bt<<<dim3((NPAD + 255) / 256, TTOK / 128, gs2), 256, 0, stream>>>(
        attn, wout_bf, p2, NPAD, QD, QD / gs2, NPAD - 1, NPAD, gs2, nullptr, nullptr);
    reduce2_kernel<<<dim3(3, TTOK), 256, 0, stream>>>(
        p2, x, b_out, out, gs2);
}

// Round 9
// 324.096 us; speedup vs baseline: 1.6922x; 1.6922x over previous
//
#include <hip/hip_runtime.h>
#include <math.h>

typedef unsigned short u16;
typedef unsigned int   u32;
using f32x4  = __attribute__((ext_vector_type(4))) float;
using bf16x8 = __attribute__((ext_vector_type(8))) __bf16;

#define HIDDEN   2880
#define QKVD     5120
#define QD       4096
#define TTOK     2048
#define NKV      8
#define QMULT    8
#define HD       64
#define NPAD     2944   // w_out rows padded to 23*128 (GEMM2 store-guards col<2944)

#define PREP_QKV_BLOCKS  14400   // QKVD*HIDDEN/4/256
#define PREP_RMS_BLOCKS  2048

static __device__ __forceinline__ float bflo(u32 u){ return __uint_as_float(u << 16); }
static __device__ __forceinline__ float bfhi(u32 u){ return __uint_as_float(u & 0xffff0000u); }
static __device__ __forceinline__ u16 f2bf(float f){
    u32 u = __float_as_uint(f);
    u32 r = (u + 0x7fffu + ((u >> 16) & 1u)) >> 16;
    return (u16)r;
}

static __device__ __forceinline__ void glds16(const void* g, void* l) {
    __builtin_amdgcn_global_load_lds(
        (__attribute__((address_space(1))) void*)g,
        (__attribute__((address_space(3))) void*)l,
        16, 0, 0);
}

// Mechanics: raw s_barrier (no waitcnt drain), counted vmcnt, sched_barrier pins.
#define SB0()   __builtin_amdgcn_sched_barrier(0)
#define BARB()  do { SB0(); __builtin_amdgcn_s_barrier(); SB0(); } while (0)
#define LGKM0() do { asm volatile("s_waitcnt lgkmcnt(0)"); SB0(); } while (0)
#define VMW(N)  do { SB0(); asm volatile("s_waitcnt vmcnt(" #N ")"); SB0(); } while (0)

// ---------------- fused prep: w_qkv cvt | rmsnorm ----------------
__global__ __launch_bounds__(256) void prep_kernel(const float* __restrict__ w_qkv,
                                                   u16* __restrict__ wqkv_bf,
                                                   const float* __restrict__ x,
                                                   const float* __restrict__ scale,
                                                   u16* __restrict__ h) {
    const int b = blockIdx.x;
    const int tid = threadIdx.x;
    if (b < PREP_QKV_BLOCKS) {
        int i = b * 256 + tid;
        float4 f = ((const float4*)w_qkv)[i];
        ushort4 o;
        o.x = f2bf(f.x); o.y = f2bf(f.y); o.z = f2bf(f.z); o.w = f2bf(f.w);
        ((ushort4*)wqkv_bf)[i] = o;
    } else {
        const int t = b - PREP_QKV_BLOCKS;
        const float4* xr = (const float4*)(x + (long)t * HIDDEN);
        float4 v[3];
        float ss = 0.f;
        #pragma unroll
        for (int it = 0; it < 3; ++it) {
            int i4 = tid + it * 256;
            if (i4 < 720) {
                v[it] = xr[i4];
                ss += v[it].x*v[it].x + v[it].y*v[it].y + v[it].z*v[it].z + v[it].w*v[it].w;
            }
        }
        #pragma unroll
        for (int off = 32; off > 0; off >>= 1) ss += __shfl_down(ss, off);
        __shared__ float red[4];
        if ((tid & 63) == 0) red[tid >> 6] = ss;
        __syncthreads();
        float tot = red[0] + red[1] + red[2] + red[3];
        float rr = rsqrtf(tot * (1.0f / HIDDEN) + 1e-5f);
        ushort4* hr = (ushort4*)(h + (long)t * HIDDEN);
        #pragma unroll
        for (int it = 0; it < 3; ++it) {
            int i4 = tid + it * 256;
            if (i4 < 720) {
                float4 s4 = ((const float4*)scale)[i4];
                ushort4 o;
                o.x = f2bf(v[it].x * rr * s4.x);
                o.y = f2bf(v[it].y * rr * s4.y);
                o.z = f2bf(v[it].z * rr * s4.z);
                o.w = f2bf(v[it].w * rr * s4.w);
                hr[i4] = o;
            }
        }
    }
}

// -- R6 GEMM (best measured: 83.8us GEMM1): phase-ahead register-pipelined
// 256x256/BK=64, 2 barriers/K-tile. Reads issued in phase p feed phase p+1's
// MFMA; raw barriers; counted vmcnt. See R6 notes; unchanged this round.

#define READ_BQ(SET, BASE, NQ) do { \
    SET[0][0] = *(const bf16x8*)((BASE) + (2*(NQ)+0)*2048 + off0); \
    SET[0][1] = *(const bf16x8*)((BASE) + (2*(NQ)+0)*2048 + off1); \
    SET[1][0] = *(const bf16x8*)((BASE) + (2*(NQ)+1)*2048 + off0); \
    SET[1][1] = *(const bf16x8*)((BASE) + (2*(NQ)+1)*2048 + off1); \
} while (0)

#define READ_AQ(BASE) do { \
    _Pragma("unroll") \
    for (int mi_ = 0; mi_ < 4; ++mi_) { \
        aq[mi_][0] = *(const bf16x8*)((BASE) + mi_*2048 + off0); \
        aq[mi_][1] = *(const bf16x8*)((BASE) + mi_*2048 + off1); \
    } \
} while (0)

#define MFMA_N(NQ, SET) do { \
    __builtin_amdgcn_s_setprio(1); \
    _Pragma("unroll") \
    for (int mi_ = 0; mi_ < 4; ++mi_) { \
        _Pragma("unroll") \
        for (int j_ = 0; j_ < 2; ++j_) { \
            acc[mi_][2*(NQ)+j_] = __builtin_amdgcn_mfma_f32_16x16x32_bf16(aq[mi_][0], SET[j_][0], acc[mi_][2*(NQ)+j_], 0, 0, 0); \
            acc[mi_][2*(NQ)+j_] = __builtin_amdgcn_mfma_f32_16x16x32_bf16(aq[mi_][1], SET[j_][1], acc[mi_][2*(NQ)+j_], 0, 0, 0); \
        } \
    } \
    __builtin_amdgcn_s_setprio(0); \
} while (0)

__global__ __launch_bounds__(512, 2) void gemm_bt_8ph(const u16* __restrict__ A,
                                                      const u16* __restrict__ B,
                                                      u16* __restrict__ C0,
                                                      int N, int K, int ksplit,
                                                      int blimit, int colmax,
                                                      int nz_gemm,
                                                      const float* __restrict__ wout_src,
                                                      u16* __restrict__ wout_dst) {
    const int tid  = threadIdx.x;

    if ((int)blockIdx.z >= nz_gemm) {
        // ---- filler blocks: w_out cvt+pad [HIDDEN][QD] f32 -> [NPAD][QD] bf16 ----
        const long nb = (long)gridDim.x * gridDim.y;
        long bidx = (long)blockIdx.y * gridDim.x + blockIdx.x;
        long i = bidx * 512 + tid;
        const long tot = (long)NPAD * QD / 4;
        const long stride = nb * 512;
        for (; i < tot; i += stride) {
            long idx = i * 4;
            int row = (int)(idx >> 12);
            int col = (int)(idx & 4095);
            ushort4 o;
            if (row < HIDDEN) {
                float4 f = *(const float4*)(wout_src + (long)row * QD + col);
                o.x = f2bf(f.x); o.y = f2bf(f.y); o.z = f2bf(f.z); o.w = f2bf(f.w);
            } else {
                o.x = 0; o.y = 0; o.z = 0; o.w = 0;
            }
            ((ushort4*)wout_dst)[i] = o;
        }
        return;
    }

    extern __shared__ u16 smem[];
    u16* const smA = smem;                  // [2][256][64] bf16 (32 KB/slot)
    u16* const smB = smem + 2 * 256 * 64;   // byte 65536, [2][256][64]
    const int lane = tid & 63;
    const int wv   = tid >> 6;              // wave 0..7
    const int wm2  = wv >> 1;               // 0..3 (M quad, 64 rows)
    const int wn2  = wv & 1;                // 0..1 (N half, 128 cols)
    const long m0  = (long)blockIdx.y * 256;
    const long n0  = (long)blockIdx.x * 256;
    const int kbase = blockIdx.z * ksplit;
    int krem = K - kbase; if (krem > ksplit) krem = ksplit;
    const int NT   = krem >> 6;             // K-tiles of 64
    u16* C = C0 + (size_t)blockIdx.z * ((size_t)TTOK * N);

    // staging: per-thread 16B granule; source column pre-swizzled (rule #21 pair)
    const int srow = tid >> 3;                              // 0..63
    const int sg8  = ((tid & 7) ^ (srow & 7)) << 3;         // src elem offset
    // fragment reads: swizzle folds to per-lane constants (row&7 == lane&7)
    const int fr   = lane & 15;
    const int off0 = ((lane >> 4) << 4) ^ ((lane & 7) << 4);
    const int off1 = off0 ^ 64;
    const char* aR = (const char*)smA + (wm2 * 64  + fr) * 128;
    const char* bR = (const char*)smB + (wn2 * 128 + fr) * 128;

    f32x4 acc[4][8];
    #pragma unroll
    for (int i = 0; i < 4; ++i)
        #pragma unroll
        for (int j = 0; j < 8; ++j) acc[i][j] = f32x4{0.f, 0.f, 0.f, 0.f};

    const u16* Asrc = A + (m0 + srow) * (long)K + kbase + sg8;
    auto stageA = [&](int t) {
        char* dst = (char*)smA + (t & 1) * 32768 + wv * 1024;
        const u16* src = Asrc + t * 64;
        #pragma unroll
        for (int hj = 0; hj < 4; ++hj)
            glds16(src + (size_t)(hj * 64) * K, dst + hj * 8192);
    };
    auto stageBh = [&](int t, int h) {
        char* dst = (char*)smB + (t & 1) * 32768 + (h * 128 + wv * 8) * 128;
        #pragma unroll
        for (int j = 0; j < 2; ++j) {
            long r = n0 + h * 128 + j * 64 + srow;
            if (r > blimit) r = blimit;   // clamp into zero-padded rows
            glds16(B + (size_t)r * K + kbase + t * 64 + sg8, dst + j * 8192);
        }
    };

    bf16x8 aq[4][2], bqE[2][2], bqO[2][2];

    // prologue (mirrors steady state): issue A(0),B(0) then A(1),Bh0(1).
    // VMW(6) leaves the newest 6 (A(1)+Bh0(1)) -> A(0),B(0) landed.
    stageA(0);
    stageBh(0, 0); stageBh(0, 1);
    if (NT > 1) {
        stageA(1);
        stageBh(1, 0);
        VMW(6);
    } else {
        VMW(0);
    }
    BARB();
    READ_BQ(bqE, bR, 0);      // B(0).q0
    READ_AQ(aR);              // A(0)
    LGKM0();                  // all waves' reads retired before ph1 stages A(2)
    BARB();

    for (int t = 0; t < NT; ++t) {
        const char* aS1 = aR + ((t + 1) & 1) * 32768;   // A slot t+1
        const char* bS  = bR + (t & 1) * 32768;         // B slot t
        const char* bS1 = bR + ((t + 1) & 1) * 32768;   // B slot t+1
        // ---- ph1: read q1->O; stage Bh1(t+1) THEN A(t+2); MFMA q0
        READ_BQ(bqO, bS, 1);
        if (t + 1 < NT) stageBh(t + 1, 1);
        if (t + 2 < NT) stageA(t + 2);
        MFMA_N(0, bqE);
        SB0();
        // ---- ph2: read q2->E; MFMA q1
        READ_BQ(bqE, bS, 2);
        MFMA_N(1, bqO);
        SB0();
        // ---- ph3: read q3->O; MFMA q2; counted checkpoint + barrier
        READ_BQ(bqO, bS, 3);
        MFMA_N(2, bqE);
        if (t + 2 < NT)      VMW(4);
        else if (t + 1 < NT) VMW(0);
        BARB();
        // ---- ph4: read B(t+1).q0->E; stage Bh0(t+2); MFMA q3; read aq(t+1)
        if (t + 1 < NT) READ_BQ(bqE, bS1, 0);
        if (t + 2 < NT) stageBh(t + 2, 0);
        MFMA_N(3, bqO);
        if (t + 1 < NT) READ_AQ(aS1);
        LGKM0();
        BARB();
    }

    // epilogue: C/D layout col=lane&15, row=(lane>>4)*4+reg  [m89-verified]
    const int cr = (lane >> 4) * 4;
    const int cc = lane & 15;
    #pragma unroll
    for (int nf = 0; nf < 8; ++nf) {
        long col = n0 + wn2 * 128 + nf * 16 + cc;
        if (col < colmax) {
            #pragma unroll
            for (int mi = 0; mi < 4; ++mi) {
                long row = m0 + wm2 * 64 + mi * 16 + cr;
                #pragma unroll
                for (int r2 = 0; r2 < 4; ++r2)
                    C[(row + r2) * (long)N + col] = f2bf(acc[mi][nf][r2]);
            }
        }
    }
}

// ------- RoPE (YaRN), consumes nsplit GEMM1 split-K partials + bias -------------
__global__ __launch_bounds__(256) void rope_kernel(const u16* __restrict__ p1,
                                                   const float* __restrict__ b_qkv,
                                                   u16* __restrict__ qr,
                                                   u16* __restrict__ kr,
                                                   u16* __restrict__ vr,
                                                   int nsplit) {
    const int t = blockIdx.x;
    const int tid = threadIdx.x;
    __shared__ float cs[32], sn[32];
    if (tid < 32) {
        float fi = (float)tid;
        float freq   = exp2f(17.1946032f * (fi * (1.0f / 32.0f)));   // 150000^(i/32)
        float interp = 1.0f / (32.0f * freq);
        float extra  = 1.0f / freq;
        float ramp   = (fi - 8.0927802f) * (1.0f / (17.3980220f - 8.0927802f));
        float rc     = fminf(fmaxf(ramp, 0.0f), 1.0f);               // = 1 - mask
        float invf   = interp * rc + extra * (1.0f - rc);
        float ang    = (float)t * invf;
        cs[tid] = cosf(ang) * 1.3465736f;                            // * concentration
        sn[tid] = sinf(ang) * 1.3465736f;
    }
    __syncthreads();
    const u16* rowA = p1 + (long)t * QKVD;
    auto pair = [&](int col) -> float2 {
        float2 bb = *(const float2*)(b_qkv + col);
        float a = bb.x, b = bb.y;
        for (int s = 0; s < nsplit; ++s) {
            u32 u = *(const u32*)(rowA + (size_t)s * TTOK * QKVD + col);
            a += bflo(u); b += bfhi(u);
        }
        return make_float2(a, b);
    };
    // Q: 64 heads x 32 pairs
    for (int p = tid; p < 2048; p += 256) {
        int hd2 = p >> 5, i = p & 31;
        float2 ab = pair(hd2 * 64 + 2 * i);
        float o1 = ab.x * cs[i] - ab.y * sn[i];
        float o2 = ab.y * cs[i] + ab.x * sn[i];
        *(u32*)(qr + (long)t * QD + hd2 * 64 + 2 * i) = (u32)f2bf(o1) | ((u32)f2bf(o2) << 16);
    }
    // K: 8 heads x 32 pairs == 256 threads; head-major layout [kv][t][64]
    {
        int kv = tid >> 5, i = tid & 31;
        float2 ab = pair(QD + kv * 64 + 2 * i);
        float o1 = ab.x * cs[i] - ab.y * sn[i];
        float o2 = ab.y * cs[i] + ab.x * sn[i];
        *(u32*)(kr + ((long)kv * TTOK + t) * HD + 2 * i) = (u32)f2bf(o1) | ((u32)f2bf(o2) << 16);
    }
    // V: 8 heads x 64 = 256 u32; head-major [kv][t][64]
    {
        int kv = tid >> 5, d2 = tid & 31;
        float2 ab = pair(QD + 512 + kv * 64 + 2 * d2);
        *(u32*)(vr + ((long)kv * TTOK + t) * HD + 2 * d2) = (u32)f2bf(ab.x) | ((u32)f2bf(ab.y) << 16);
    }
}

// -------- R9 attn: merged-z (8 q-heads/block), packed-u32 V transpose ----------
// R6 attn duplicated all K/V staging across blockIdx.z (two blocks staged the
// SAME window) and did the V transpose via 9216 scalar ds_write_b16 per block.
// Now: 1024 blocks x 512 thr (8 waves = 8 q-heads), dynamic LDS 85248 B
// (1 block/CU, same 8 waves/CU as before). Staging once per (t0,h):
//  - K: 1152 uint4 over 512 threads.
//  - V transpose: 288 threads, each 2 keys x 16 dims -> 16 u32 pair-packed
//    stores (4608 b32 total vs 2x9216 b16). c2-phase stagger (compile-time two
//    variants, rule #20 safe) keeps store conflicts <=2-way.
__global__ __launch_bounds__(512, 1) void attn_kernel(const u16* __restrict__ qr,
                                                      const u16* __restrict__ kr,
                                                      const u16* __restrict__ vr,
                                                      const float* __restrict__ sinks,
                                                      u16* __restrict__ o) {
    const int t0  = blockIdx.x * 16;
    const int h   = blockIdx.y;
    const int tid = threadIdx.x;
    const int lane = tid & 63, wv = tid >> 6;    // wv = q-head 0..7
    extern __shared__ __align__(16) u16 asmem[];
    u16* const ks = asmem;                        // [144][72]
    u16* const Vt = asmem + 144 * 72;             // [64][168], cols 144..159 zero
    u16* const Pb = asmem + 144 * 72 + 64 * 168;  // [8][16][168], cols 144..159 zero
    const u16* kb = kr + (long)h * TTOK * HD;
    const u16* vb = vr + (long)h * TTOK * HD;

    // stage K rows (coalesced): 1152 uint4 over 512 threads
    #pragma unroll
    for (int i = 0; i < 3; ++i) {
        int idx = i * 512 + tid;
        if (idx < 144 * 8) {
            int rr = idx >> 3, c = idx & 7;
            int tk = t0 - 128 + rr;
            int tks = tk < 0 ? 0 : tk;          // clamped; masked later
            *(uint4*)(ks + rr * 72 + c * 8) = *(const uint4*)(kb + (long)tks * HD + c * 8);
        }
    }
    // stage V transposed, pair-packed: thread -> 2 keys x 16 dims
    if (tid < 288) {
        const int kp = tid >> 2, c2 = tid & 3;   // kp 0..71, c2 0..3
        const int k0 = kp * 2;
        int tk0 = t0 - 128 + k0;     tk0 = tk0 < 0 ? 0 : tk0;
        int tk1 = t0 - 128 + k0 + 1; tk1 = tk1 < 0 ? 0 : tk1;
        uint4 a0 = *(const uint4*)(vb + (long)tk0 * HD + c2 * 16);
        uint4 a1 = *(const uint4*)(vb + (long)tk0 * HD + c2 * 16 + 8);
        uint4 b0 = *(const uint4*)(vb + (long)tk1 * HD + c2 * 16);
        uint4 b1 = *(const uint4*)(vb + (long)tk1 * HD + c2 * 16 + 8);
        u32 wa[8] = {a0.x, a0.y, a0.z, a0.w, a1.x, a1.y, a1.z, a1.w};
        u32 wb[8] = {b0.x, b0.y, b0.z, b0.w, b1.x, b1.y, b1.z, b1.w};
        u16* vrow = Vt + c2 * 16 * 168 + k0;
        // two compile-time d-orders (c2 phase stagger): banks differ by 16 -> <=2-way
        if (c2 & 2) {
            #pragma unroll
            for (int dd = 0; dd < 16; ++dd) {
                int d = (dd + 4) & 15;
                u32 oo = (d & 1) ? ((wa[d >> 1] >> 16) | (wb[d >> 1] & 0xffff0000u))
                                 : ((wa[d >> 1] & 0xffffu) | (wb[d >> 1] << 16));
                *(u32*)(vrow + d * 168) = oo;
            }
        } else {
            #pragma unroll
            for (int d = 0; d < 16; ++d) {
                u32 oo = (d & 1) ? ((wa[d >> 1] >> 16) | (wb[d >> 1] & 0xffff0000u))
                                 : ((wa[d >> 1] & 0xffffu) | (wb[d >> 1] << 16));
                *(u32*)(vrow + d * 168) = oo;
            }
        }
    }
    if (tid < 128) {
        *(uint4*)(Vt + (tid >> 1) * 168 + 144 + (tid & 1) * 8) = uint4{0, 0, 0, 0};
    }
    if (lane < 32) {
        *(uint4*)(Pb + wv * 16 * 168 + (lane >> 1) * 168 + 144 + (lane & 1) * 8) = uint4{0, 0, 0, 0};
    }
    __syncthreads();

    const int head = h * QMULT + wv;
    const int fr = lane & 15, fk = (lane >> 4) * 8;
    const int cr = (lane >> 4) * 4;
    u16* const Pw = Pb + wv * 16 * 168;

    const u16* qrow = qr + (long)(t0 + fr) * QD + head * HD;
    bf16x8 qf0 = *(const bf16x8*)(qrow + fk);
    bf16x8 qf1 = *(const bf16x8*)(qrow + 32 + fk);

    const int kmin = 128 - t0;          // kk >= kmin <=> key token >= 0
    float lsum[4] = {0.f, 0.f, 0.f, 0.f};

    for (int nt = 0; nt < 9; ++nt) {
        bf16x8 b0 = *(const bf16x8*)(ks + (nt * 16 + fr) * 72 + fk);
        bf16x8 b1 = *(const bf16x8*)(ks + (nt * 16 + fr) * 72 + 32 + fk);
        f32x4 s = f32x4{0.f, 0.f, 0.f, 0.f};
        s = __builtin_amdgcn_mfma_f32_16x16x32_bf16(qf0, b0, s, 0, 0, 0);
        s = __builtin_amdgcn_mfma_f32_16x16x32_bf16(qf1, b1, s, 0, 0, 0);
        const int kk = nt * 16 + fr;    // C-layout col = lane&15
        #pragma unroll
        for (int r = 0; r < 4; ++r) {
            int row = cr + r;           // token index within tile
            bool valid = (kk >= row) && (kk <= row + 128) && (kk >= kmin);
            float p = valid ? __expf(s[r] * 0.125f) : 0.0f;
            lsum[r] += p;
            Pw[row * 168 + kk] = f2bf(p);
        }
    }

    f32x4 oacc[4];
    #pragma unroll
    for (int dt = 0; dt < 4; ++dt) oacc[dt] = f32x4{0.f, 0.f, 0.f, 0.f};
    #pragma unroll
    for (int k5 = 0; k5 < 5; ++k5) {
        const int k0 = k5 * 32;
        bf16x8 pa = *(const bf16x8*)(Pw + fr * 168 + k0 + fk);
        #pragma unroll
        for (int dt = 0; dt < 4; ++dt) {
            bf16x8 vf = *(const bf16x8*)(Vt + (dt * 16 + fr) * 168 + k0 + fk);
            oacc[dt] = __builtin_amdgcn_mfma_f32_16x16x32_bf16(pa, vf, oacc[dt], 0, 0, 0);
        }
    }

    #pragma unroll
    for (int r = 0; r < 4; ++r) {
        float v = lsum[r];
        v += __shfl_xor(v, 1);
        v += __shfl_xor(v, 2);
        v += __shfl_xor(v, 4);
        v += __shfl_xor(v, 8);
        lsum[r] = v;
    }
    const float sk = exp2f(sinks[head]);
    float inv[4];
    #pragma unroll
    for (int r = 0; r < 4; ++r) inv[r] = 1.0f / (lsum[r] + sk);

    #pragma unroll
    for (int dt = 0; dt < 4; ++dt) {
        #pragma unroll
        for (int r = 0; r < 4; ++r) {
            o[(long)(t0 + cr + r) * QD + head * HD + dt * 16 + fr] = f2bf(oacc[dt][r] * inv[r]);
        }
    }
}

// ---------------- reduce GEMM2 partials + bias + residual -> out ----------------
__global__ __launch_bounds__(256) void reduce2_kernel(const u16* __restrict__ p2a,
                                                      const u16* __restrict__ p2b,
                                                      const float* __restrict__ x,
                                                      const float* __restrict__ b_out,
                                                      float* __restrict__ out) {
    const int row = blockIdx.y;
    const int c4 = blockIdx.x * 256 + threadIdx.x;   // float4 index within row
    if (c4 >= 720) return;
    const int col = c4 * 4;
    ushort4 ua = *(const ushort4*)(p2a + (long)row * NPAD + col);
    ushort4 ub = *(const ushort4*)(p2b + (long)row * NPAD + col);
    float4 xv = *(const float4*)(x + (long)row * HIDDEN + col);
    float4 bv = *(const float4*)(b_out + col);
    float4 o;
    o.x = xv.x + bv.x + __uint_as_float((u32)ua.x << 16) + __uint_as_float((u32)ub.x << 16);
    o.y = xv.y + bv.y + __uint_as_float((u32)ua.y << 16) + __uint_as_float((u32)ub.y << 16);
    o.z = xv.z + bv.z + __uint_as_float((u32)ua.z << 16) + __uint_as_float((u32)ub.z << 16);
    o.w = xv.w + bv.w + __uint_as_float((u32)ua.w << 16) + __uint_as_float((u32)ub.w << 16);
    *(float4*)(out + (long)row * HIDDEN + col) = o;
}

// ---------------- launcher ----------------
extern "C" void kernel_launch(void* const* d_in, const int* in_sizes, int n_in,
                              void* d_out, int out_size, void* d_ws, size_t ws_size,
                              hipStream_t stream) {
    const float* x      = (const float*)d_in[0];
    const float* nscale = (const float*)d_in[1];
    const float* w_qkv  = (const float*)d_in[2];
    const float* b_qkv  = (const float*)d_in[3];
    const float* sinks  = (const float*)d_in[4];
    const float* w_out  = (const float*)d_in[5];
    const float* b_out  = (const float*)d_in[6];
    float* out = (float*)d_out;

    static int smem_set = 0;
    if (!smem_set) {
        hipFuncSetAttribute((const void*)gemm_bt_8ph,
                            hipFuncAttributeMaxDynamicSharedMemorySize, 131072);
        hipFuncSetAttribute((const void*)attn_kernel,
                            hipFuncAttributeMaxDynamicSharedMemorySize, 85248);
        smem_set = 1;
    }

    char* ws = (char*)d_ws;
    size_t off = 0;
    auto alloc = [&](size_t bytes) { void* p = ws + off; off += (bytes + 255) & ~(size_t)255; return p; };
    const size_t p1_bytes  = (size_t)TTOK * QKVD * 2;          // 21.0 MB (GEMM1 out)
    const size_t p2_bytes  = (size_t)2 * TTOK * NPAD * 2;      // 24.1 MB (GEMM2 partials)
    u16* wqkv_bf = (u16*)alloc((size_t)QKVD * HIDDEN * 2);     // 29.5 MB
    u16* wout_bf = (u16*)alloc((size_t)NPAD * QD * 2);         // 24.1 MB
    u16* h       = (u16*)alloc((size_t)TTOK * HIDDEN * 2);     // 11.8 MB
    u16* p1      = (u16*)alloc(p1_bytes > p2_bytes ? p1_bytes : p2_bytes);
    u16* qrot    = (u16*)alloc((size_t)TTOK * QD * 2);         // 16.8 MB
    // aliases (dead-after analysis):
    u16* attn = wqkv_bf;                       // wqkv_bf dead after gemm1 (16.8 MB)
    u16* krot = wqkv_bf + (size_t)TTOK * QD;   // wqkv tail: +2.1 MB
    u16* vrot = krot + (size_t)NKV * TTOK * HD;// +2.1 MB (total 21.0 <= 29.5 OK)
    u16* p2   = p1;                            // p1 dead after rope; sized above

    prep_kernel<<<PREP_QKV_BLOCKS + PREP_RMS_BLOCKS, 256, 0, stream>>>(
        w_qkv, wqkv_bf, x, nscale, h);
    // GEMM1: full-K (z=0 only), 20x8 = 160 gemm blocks + 160 z=1 filler blocks
    gemm_bt_8ph<<<dim3(QKVD / 256, TTOK / 256, 2), 512, 131072, stream>>>(
        h, wqkv_bf, p1, QKVD, HIDDEN, HIDDEN, QKVD - 1, QKVD, 1, w_out, wout_bf);
    rope_kernel<<<TTOK, 256, 0, stream>>>(p1, b_qkv, qrot, krot, vrot, 1);
    // attn: merged-z, 128x8 = 1024 blocks x 512 thr, 85 KB dynamic LDS
    attn_kernel<<<dim3(TTOK / 16, NKV), 512, 85248, stream>>>(
        qrot, krot, vrot, sinks, attn);
    // GEMM2: split-K z=2 (both z-slices are gemm; no filler), 12x8x2 = 192 blocks
    gemm_bt_8ph<<<dim3((NPAD + 255) / 256, TTOK / 256, 2), 512, 131072, stream>>>(
        attn, wout_bf, p2, NPAD, QD, QD / 2, NPAD - 1, NPAD, 2, nullptr, nullptr);
    reduce2_kernel<<<dim3(3, TTOK), 256, 0, stream>>>(
        p2, p2 + (size_t)TTOK * NPAD, x, b_out, out);
}

// Round 10
// 319.014 us; speedup vs baseline: 1.7192x; 1.0159x over previous
//
#include <hip/hip_runtime.h>
#include <math.h>

typedef unsigned short u16;
typedef unsigned int   u32;
using f32x4  = __attribute__((ext_vector_type(4))) float;
using bf16x8 = __attribute__((ext_vector_type(8))) __bf16;

#define HIDDEN   2880
#define QKVD     5120
#define QD       4096
#define TTOK     2048
#define NKV      8
#define QMULT    8
#define HD       64
#define NPAD     3072   // w_out rows padded to 16*192 -> GEMM2 grid 16x8x2 = 256 blocks (full fill)

#define PREP_QKV_BLOCKS  14400   // QKVD*HIDDEN/4/256
#define PREP_RMS_BLOCKS  2048

static __device__ __forceinline__ float bflo(u32 u){ return __uint_as_float(u << 16); }
static __device__ __forceinline__ float bfhi(u32 u){ return __uint_as_float(u & 0xffff0000u); }
static __device__ __forceinline__ u16 f2bf(float f){
    u32 u = __float_as_uint(f);
    u32 r = (u + 0x7fffu + ((u >> 16) & 1u)) >> 16;
    return (u16)r;
}

static __device__ __forceinline__ void glds16(const void* g, void* l) {
    __builtin_amdgcn_global_load_lds(
        (__attribute__((address_space(1))) void*)g,
        (__attribute__((address_space(3))) void*)l,
        16, 0, 0);
}

// Mechanics: raw s_barrier (no waitcnt drain), counted vmcnt, sched_barrier pins.
#define SB0()   __builtin_amdgcn_sched_barrier(0)
#define BARB()  do { SB0(); __builtin_amdgcn_s_barrier(); SB0(); } while (0)
#define LGKM0() do { asm volatile("s_waitcnt lgkmcnt(0)"); SB0(); } while (0)
#define VMW(N)  do { SB0(); asm volatile("s_waitcnt vmcnt(" #N ")"); SB0(); } while (0)

// ---------------- fused prep: w_qkv cvt | rmsnorm ----------------
__global__ __launch_bounds__(256) void prep_kernel(const float* __restrict__ w_qkv,
                                                   u16* __restrict__ wqkv_bf,
                                                   const float* __restrict__ x,
                                                   const float* __restrict__ scale,
                                                   u16* __restrict__ h) {
    const int b = blockIdx.x;
    const int tid = threadIdx.x;
    if (b < PREP_QKV_BLOCKS) {
        int i = b * 256 + tid;
        float4 f = ((const float4*)w_qkv)[i];
        ushort4 o;
        o.x = f2bf(f.x); o.y = f2bf(f.y); o.z = f2bf(f.z); o.w = f2bf(f.w);
        ((ushort4*)wqkv_bf)[i] = o;
    } else {
        const int t = b - PREP_QKV_BLOCKS;
        const float4* xr = (const float4*)(x + (long)t * HIDDEN);
        float4 v[3];
        float ss = 0.f;
        #pragma unroll
        for (int it = 0; it < 3; ++it) {
            int i4 = tid + it * 256;
            if (i4 < 720) {
                v[it] = xr[i4];
                ss += v[it].x*v[it].x + v[it].y*v[it].y + v[it].z*v[it].z + v[it].w*v[it].w;
            }
        }
        #pragma unroll
        for (int off = 32; off > 0; off >>= 1) ss += __shfl_down(ss, off);
        __shared__ float red[4];
        if ((tid & 63) == 0) red[tid >> 6] = ss;
        __syncthreads();
        float tot = red[0] + red[1] + red[2] + red[3];
        float rr = rsqrtf(tot * (1.0f / HIDDEN) + 1e-5f);
        ushort4* hr = (ushort4*)(h + (long)t * HIDDEN);
        #pragma unroll
        for (int it = 0; it < 3; ++it) {
            int i4 = tid + it * 256;
            if (i4 < 720) {
                float4 s4 = ((const float4*)scale)[i4];
                ushort4 o;
                o.x = f2bf(v[it].x * rr * s4.x);
                o.y = f2bf(v[it].y * rr * s4.y);
                o.z = f2bf(v[it].z * rr * s4.z);
                o.w = f2bf(v[it].w * rr * s4.w);
                hr[i4] = o;
            }
        }
    }
}

// -- R6 GEMM (GEMM1; best measured 82.5us): phase-ahead register-pipelined
// 256x256/BK=64, 2 barriers/K-tile. Unchanged except the filler cap (nfill=96:
// only as many filler blocks as idle CUs -> no serial tail after gemm blocks).

#define READ_BQ(SET, BASE, NQ) do { \
    SET[0][0] = *(const bf16x8*)((BASE) + (2*(NQ)+0)*2048 + off0); \
    SET[0][1] = *(const bf16x8*)((BASE) + (2*(NQ)+0)*2048 + off1); \
    SET[1][0] = *(const bf16x8*)((BASE) + (2*(NQ)+1)*2048 + off0); \
    SET[1][1] = *(const bf16x8*)((BASE) + (2*(NQ)+1)*2048 + off1); \
} while (0)

#define READ_AQ(BASE) do { \
    _Pragma("unroll") \
    for (int mi_ = 0; mi_ < 4; ++mi_) { \
        aq[mi_][0] = *(const bf16x8*)((BASE) + mi_*2048 + off0); \
        aq[mi_][1] = *(const bf16x8*)((BASE) + mi_*2048 + off1); \
    } \
} while (0)

#define MFMA_N(NQ, SET) do { \
    __builtin_amdgcn_s_setprio(1); \
    _Pragma("unroll") \
    for (int mi_ = 0; mi_ < 4; ++mi_) { \
        _Pragma("unroll") \
        for (int j_ = 0; j_ < 2; ++j_) { \
            acc[mi_][2*(NQ)+j_] = __builtin_amdgcn_mfma_f32_16x16x32_bf16(aq[mi_][0], SET[j_][0], acc[mi_][2*(NQ)+j_], 0, 0, 0); \
            acc[mi_][2*(NQ)+j_] = __builtin_amdgcn_mfma_f32_16x16x32_bf16(aq[mi_][1], SET[j_][1], acc[mi_][2*(NQ)+j_], 0, 0, 0); \
        } \
    } \
    __builtin_amdgcn_s_setprio(0); \
} while (0)

__global__ __launch_bounds__(512, 2) void gemm_bt_8ph(const u16* __restrict__ A,
                                                      const u16* __restrict__ B,
                                                      u16* __restrict__ C0,
                                                      int N, int K, int ksplit,
                                                      int blimit, int colmax,
                                                      int nz_gemm, int nfill,
                                                      const float* __restrict__ wout_src,
                                                      u16* __restrict__ wout_dst) {
    const int tid  = threadIdx.x;

    if ((int)blockIdx.z >= nz_gemm) {
        // ---- filler blocks: w_out cvt+pad [HIDDEN][QD] f32 -> [NPAD][QD] bf16 ----
        long bidx = (long)blockIdx.y * gridDim.x + blockIdx.x;
        if (bidx >= nfill) return;           // cap at idle-CU count (no tail)
        long i = bidx * 512 + tid;
        const long tot = (long)NPAD * QD / 4;
        const long stride = (long)nfill * 512;
        for (; i < tot; i += stride) {
            long idx = i * 4;
            int row = (int)(idx >> 12);
            int col = (int)(idx & 4095);
            ushort4 o;
            if (row < HIDDEN) {
                float4 f = *(const float4*)(wout_src + (long)row * QD + col);
                o.x = f2bf(f.x); o.y = f2bf(f.y); o.z = f2bf(f.z); o.w = f2bf(f.w);
            } else {
                o.x = 0; o.y = 0; o.z = 0; o.w = 0;
            }
            ((ushort4*)wout_dst)[i] = o;
        }
        return;
    }

    extern __shared__ u16 smem[];
    u16* const smA = smem;                  // [2][256][64] bf16 (32 KB/slot)
    u16* const smB = smem + 2 * 256 * 64;   // byte 65536, [2][256][64]
    const int lane = tid & 63;
    const int wv   = tid >> 6;              // wave 0..7
    const int wm2  = wv >> 1;               // 0..3 (M quad, 64 rows)
    const int wn2  = wv & 1;                // 0..1 (N half, 128 cols)
    const long m0  = (long)blockIdx.y * 256;
    const long n0  = (long)blockIdx.x * 256;
    const int kbase = blockIdx.z * ksplit;
    int krem = K - kbase; if (krem > ksplit) krem = ksplit;
    const int NT   = krem >> 6;             // K-tiles of 64
    u16* C = C0 + (size_t)blockIdx.z * ((size_t)TTOK * N);

    const int srow = tid >> 3;                              // 0..63
    const int sg8  = ((tid & 7) ^ (srow & 7)) << 3;         // src elem offset
    const int fr   = lane & 15;
    const int off0 = ((lane >> 4) << 4) ^ ((lane & 7) << 4);
    const int off1 = off0 ^ 64;
    const char* aR = (const char*)smA + (wm2 * 64  + fr) * 128;
    const char* bR = (const char*)smB + (wn2 * 128 + fr) * 128;

    f32x4 acc[4][8];
    #pragma unroll
    for (int i = 0; i < 4; ++i)
        #pragma unroll
        for (int j = 0; j < 8; ++j) acc[i][j] = f32x4{0.f, 0.f, 0.f, 0.f};

    const u16* Asrc = A + (m0 + srow) * (long)K + kbase + sg8;
    auto stageA = [&](int t) {
        char* dst = (char*)smA + (t & 1) * 32768 + wv * 1024;
        const u16* src = Asrc + t * 64;
        #pragma unroll
        for (int hj = 0; hj < 4; ++hj)
            glds16(src + (size_t)(hj * 64) * K, dst + hj * 8192);
    };
    auto stageBh = [&](int t, int h) {
        char* dst = (char*)smB + (t & 1) * 32768 + (h * 128 + wv * 8) * 128;
        #pragma unroll
        for (int j = 0; j < 2; ++j) {
            long r = n0 + h * 128 + j * 64 + srow;
            if (r > blimit) r = blimit;
            glds16(B + (size_t)r * K + kbase + t * 64 + sg8, dst + j * 8192);
        }
    };

    bf16x8 aq[4][2], bqE[2][2], bqO[2][2];

    stageA(0);
    stageBh(0, 0); stageBh(0, 1);
    if (NT > 1) {
        stageA(1);
        stageBh(1, 0);
        VMW(6);
    } else {
        VMW(0);
    }
    BARB();
    READ_BQ(bqE, bR, 0);
    READ_AQ(aR);
    LGKM0();
    BARB();

    for (int t = 0; t < NT; ++t) {
        const char* aS1 = aR + ((t + 1) & 1) * 32768;
        const char* bS  = bR + (t & 1) * 32768;
        const char* bS1 = bR + ((t + 1) & 1) * 32768;
        READ_BQ(bqO, bS, 1);
        if (t + 1 < NT) stageBh(t + 1, 1);
        if (t + 2 < NT) stageA(t + 2);
        MFMA_N(0, bqE);
        SB0();
        READ_BQ(bqE, bS, 2);
        MFMA_N(1, bqO);
        SB0();
        READ_BQ(bqO, bS, 3);
        MFMA_N(2, bqE);
        if (t + 2 < NT)      VMW(4);
        else if (t + 1 < NT) VMW(0);
        BARB();
        if (t + 1 < NT) READ_BQ(bqE, bS1, 0);
        if (t + 2 < NT) stageBh(t + 2, 0);
        MFMA_N(3, bqO);
        if (t + 1 < NT) READ_AQ(aS1);
        LGKM0();
        BARB();
    }

    const int cr = (lane >> 4) * 4;
    const int cc = lane & 15;
    #pragma unroll
    for (int nf = 0; nf < 8; ++nf) {
        long col = n0 + wn2 * 128 + nf * 16 + cc;
        if (col < colmax) {
            #pragma unroll
            for (int mi = 0; mi < 4; ++mi) {
                long row = m0 + wm2 * 64 + mi * 16 + cr;
                #pragma unroll
                for (int r2 = 0; r2 < 4; ++r2)
                    C[(row + r2) * (long)N + col] = f2bf(acc[mi][nf][r2]);
            }
        }
    }
}

// -- R10 GEMM2 variant: 256x192 tile (3 B-quads), full-fill grid 16x8x2=256 ----
// Same R6 phase-ahead mechanics; 3 fragment sets S0/S1/S2 with PHASE-FIXED
// assignment (ph4 reads q0->S2, ph1 reads q1->S0, ph2 reads q2->S1) so register
// indices are compile-time uniform across tiles (no parity issue with odd quad
// count). Per tile: 7 staged loads (B x3 + A x4, issued ph1).
// vmcnt(4)@ph3: outstanding = B(t+1)x3 + A(t+2)x4 (+ maybe A(t+1) older);
// leaves newest 4 (A(t+2)) -> B(t+1), A(t+1) confirmed; BARB propagates.
// LGKM0+BARB@ph4-end: all waves' frag reads retired before next ph1's stages
// overwrite their slots (cross-wave queue-drain fence, as in R6).
// LDS 112 KB: A[2][256][64] (64K) + B[2][192][64] (48K). acc[4][6]=96 VGPR.
__global__ __launch_bounds__(512, 2) void gemm_bt_3q(const u16* __restrict__ A,
                                                     const u16* __restrict__ B,
                                                     u16* __restrict__ C0,
                                                     int N, int K, int ksplit,
                                                     int blimit) {
    extern __shared__ u16 smem[];
    u16* const smA = smem;                  // [2][256][64] (32 KB/slot)
    u16* const smB = smem + 2 * 256 * 64;   // [2][192][64] (24 KB/slot)
    const int tid  = threadIdx.x;
    const int lane = tid & 63;
    const int wv   = tid >> 6;              // wave 0..7
    const int wm2  = wv >> 1;               // 0..3 (M quad, 64 rows)
    const int wn2  = wv & 1;                // 0..1 (N half, 96 cols)
    const long m0  = (long)blockIdx.y * 256;
    const long n0  = (long)blockIdx.x * 192;
    const int kbase = blockIdx.z * ksplit;
    int krem = K - kbase; if (krem > ksplit) krem = ksplit;
    const int NT   = krem >> 6;             // K-tiles of 64
    u16* C = C0 + (size_t)blockIdx.z * ((size_t)TTOK * N);

    const int srow = tid >> 3;                              // 0..63
    const int sg8  = ((tid & 7) ^ (srow & 7)) << 3;
    const int fr   = lane & 15;
    const int off0 = ((lane >> 4) << 4) ^ ((lane & 7) << 4);
    const int off1 = off0 ^ 64;
    const char* aR = (const char*)smA + (wm2 * 64 + fr) * 128;
    const char* bR = (const char*)smB + (wn2 * 96 + fr) * 128;

    f32x4 acc[4][6];
    #pragma unroll
    for (int i = 0; i < 4; ++i)
        #pragma unroll
        for (int j = 0; j < 6; ++j) acc[i][j] = f32x4{0.f, 0.f, 0.f, 0.f};

    const u16* Asrc = A + (m0 + srow) * (long)K + kbase + sg8;
    auto stageA = [&](int t) {
        char* dst = (char*)smA + (t & 1) * 32768 + wv * 1024;
        const u16* src = Asrc + t * 64;
        #pragma unroll
        for (int hj = 0; hj < 4; ++hj)
            glds16(src + (size_t)(hj * 64) * K, dst + hj * 8192);
    };
    auto stageB3 = [&](int t) {                 // 192 rows = 3 x 64-row passes
        char* base = (char*)smB + (t & 1) * 24576;
        #pragma unroll
        for (int j = 0; j < 3; ++j) {
            long r = n0 + j * 64 + srow;
            if (r > blimit) r = blimit;
            glds16(B + (size_t)r * K + kbase + t * 64 + sg8,
                   base + (j * 64 + wv * 8) * 128);
        }
    };

    bf16x8 aq[4][2], s0[2][2], s1[2][2], s2[2][2];

    // prologue: B(0)x3, A(0)x4, A(1)x4 = 11 loads; VMW(4) leaves A(1) ->
    // B(0),A(0) landed. Read q0(0)->S2 + aq(0); LGKM0 fence before loop.
    stageB3(0);
    stageA(0);
    if (NT > 1) { stageA(1); VMW(4); }
    else        { VMW(0); }
    BARB();
    READ_BQ(s2, bR, 0);
    READ_AQ(aR);
    LGKM0();
    BARB();

    for (int t = 0; t < NT; ++t) {
        const char* aS1 = aR + ((t + 1) & 1) * 32768;
        const char* bS  = bR + (t & 1) * 24576;
        const char* bS1 = bR + ((t + 1) & 1) * 24576;
        // ph1: MFMA q0(S2); read q1->S0; stage B(t+1) then A(t+2)
        READ_BQ(s0, bS, 1);
        if (t + 1 < NT) stageB3(t + 1);
        if (t + 2 < NT) stageA(t + 2);
        MFMA_N(0, s2);
        SB0();
        // ph2: read q2->S1; MFMA q1(S0)
        READ_BQ(s1, bS, 2);
        MFMA_N(1, s0);
        SB0();
        // ph3: MFMA q2(S1); counted checkpoint + barrier
        MFMA_N(2, s1);
        if (t + 2 < NT)      VMW(4);
        else if (t + 1 < NT) VMW(0);
        BARB();
        // ph4: read q0(t+1)->S2 + aq(t+1); LGKM0 fence + barrier
        if (t + 1 < NT) { READ_BQ(s2, bS1, 0); READ_AQ(aS1); }
        LGKM0();
        BARB();
    }

    // epilogue: C/D layout col=lane&15, row=(lane>>4)*4+reg  [m89-verified]
    const int cr = (lane >> 4) * 4;
    const int cc = lane & 15;
    #pragma unroll
    for (int nf = 0; nf < 6; ++nf) {
        long col = n0 + wn2 * 96 + nf * 16 + cc;
        #pragma unroll
        for (int mi = 0; mi < 4; ++mi) {
            long row = m0 + wm2 * 64 + mi * 16 + cr;
            #pragma unroll
            for (int r2 = 0; r2 < 4; ++r2)
                C[(row + r2) * (long)N + col] = f2bf(acc[mi][nf][r2]);
        }
    }
}

// ------- RoPE (YaRN), consumes GEMM1 output + bias -------------
__global__ __launch_bounds__(256) void rope_kernel(const u16* __restrict__ p1,
                                                   const float* __restrict__ b_qkv,
                                                   u16* __restrict__ qr,
                                                   u16* __restrict__ kr,
                                                   u16* __restrict__ vr,
                                                   int nsplit) {
    const int t = blockIdx.x;
    const int tid = threadIdx.x;
    __shared__ float cs[32], sn[32];
    if (tid < 32) {
        float fi = (float)tid;
        float freq   = exp2f(17.1946032f * (fi * (1.0f / 32.0f)));   // 150000^(i/32)
        float interp = 1.0f / (32.0f * freq);
        float extra  = 1.0f / freq;
        float ramp   = (fi - 8.0927802f) * (1.0f / (17.3980220f - 8.0927802f));
        float rc     = fminf(fmaxf(ramp, 0.0f), 1.0f);               // = 1 - mask
        float invf   = interp * rc + extra * (1.0f - rc);
        float ang    = (float)t * invf;
        cs[tid] = cosf(ang) * 1.3465736f;                            // * concentration
        sn[tid] = sinf(ang) * 1.3465736f;
    }
    __syncthreads();
    const u16* rowA = p1 + (long)t * QKVD;
    auto pair = [&](int col) -> float2 {
        float2 bb = *(const float2*)(b_qkv + col);
        float a = bb.x, b = bb.y;
        for (int s = 0; s < nsplit; ++s) {
            u32 u = *(const u32*)(rowA + (size_t)s * TTOK * QKVD + col);
            a += bflo(u); b += bfhi(u);
        }
        return make_float2(a, b);
    };
    // Q: 64 heads x 32 pairs
    for (int p = tid; p < 2048; p += 256) {
        int hd2 = p >> 5, i = p & 31;
        float2 ab = pair(hd2 * 64 + 2 * i);
        float o1 = ab.x * cs[i] - ab.y * sn[i];
        float o2 = ab.y * cs[i] + ab.x * sn[i];
        *(u32*)(qr + (long)t * QD + hd2 * 64 + 2 * i) = (u32)f2bf(o1) | ((u32)f2bf(o2) << 16);
    }
    // K: 8 heads x 32 pairs == 256 threads; head-major layout [kv][t][64]
    {
        int kv = tid >> 5, i = tid & 31;
        float2 ab = pair(QD + kv * 64 + 2 * i);
        float o1 = ab.x * cs[i] - ab.y * sn[i];
        float o2 = ab.y * cs[i] + ab.x * sn[i];
        *(u32*)(kr + ((long)kv * TTOK + t) * HD + 2 * i) = (u32)f2bf(o1) | ((u32)f2bf(o2) << 16);
    }
    // V: 8 heads x 64 = 256 u32; head-major [kv][t][64]
    {
        int kv = tid >> 5, d2 = tid & 31;
        float2 ab = pair(QD + 512 + kv * 64 + 2 * d2);
        *(u32*)(vr + ((long)kv * TTOK + t) * HD + 2 * d2) = (u32)f2bf(ab.x) | ((u32)f2bf(ab.y) << 16);
    }
}

// -------- attn (R9): merged-z (8 q-heads/block), packed-u32 V transpose --------
__global__ __launch_bounds__(512, 1) void attn_kernel(const u16* __restrict__ qr,
                                                      const u16* __restrict__ kr,
                                                      const u16* __restrict__ vr,
                                                      const float* __restrict__ sinks,
                                                      u16* __restrict__ o) {
    const int t0  = blockIdx.x * 16;
    const int h   = blockIdx.y;
    const int tid = threadIdx.x;
    const int lane = tid & 63, wv = tid >> 6;    // wv = q-head 0..7
    extern __shared__ __align__(16) u16 asmem[];
    u16* const ks = asmem;                        // [144][72]
    u16* const Vt = asmem + 144 * 72;             // [64][168], cols 144..159 zero
    u16* const Pb = asmem + 144 * 72 + 64 * 168;  // [8][16][168], cols 144..159 zero
    const u16* kb = kr + (long)h * TTOK * HD;
    const u16* vb = vr + (long)h * TTOK * HD;

    #pragma unroll
    for (int i = 0; i < 3; ++i) {
        int idx = i * 512 + tid;
        if (idx < 144 * 8) {
            int rr = idx >> 3, c = idx & 7;
            int tk = t0 - 128 + rr;
            int tks = tk < 0 ? 0 : tk;
            *(uint4*)(ks + rr * 72 + c * 8) = *(const uint4*)(kb + (long)tks * HD + c * 8);
        }
    }
    if (tid < 288) {
        const int kp = tid >> 2, c2 = tid & 3;
        const int k0 = kp * 2;
        int tk0 = t0 - 128 + k0;     tk0 = tk0 < 0 ? 0 : tk0;
        int tk1 = t0 - 128 + k0 + 1; tk1 = tk1 < 0 ? 0 : tk1;
        uint4 a0 = *(const uint4*)(vb + (long)tk0 * HD + c2 * 16);
        uint4 a1 = *(const uint4*)(vb + (long)tk0 * HD + c2 * 16 + 8);
        uint4 b0 = *(const uint4*)(vb + (long)tk1 * HD + c2 * 16);
        uint4 b1 = *(const uint4*)(vb + (long)tk1 * HD + c2 * 16 + 8);
        u32 wa[8] = {a0.x, a0.y, a0.z, a0.w, a1.x, a1.y, a1.z, a1.w};
        u32 wb[8] = {b0.x, b0.y, b0.z, b0.w, b1.x, b1.y, b1.z, b1.w};
        u16* vrow = Vt + c2 * 16 * 168 + k0;
        if (c2 & 2) {
            #pragma unroll
            for (int dd = 0; dd < 16; ++dd) {
                int d = (dd + 4) & 15;
                u32 oo = (d & 1) ? ((wa[d >> 1] >> 16) | (wb[d >> 1] & 0xffff0000u))
                                 : ((wa[d >> 1] & 0xffffu) | (wb[d >> 1] << 16));
                *(u32*)(vrow + d * 168) = oo;
            }
        } else {
            #pragma unroll
            for (int d = 0; d < 16; ++d) {
                u32 oo = (d & 1) ? ((wa[d >> 1] >> 16) | (wb[d >> 1] & 0xffff0000u))
                                 : ((wa[d >> 1] & 0xffffu) | (wb[d >> 1] << 16));
                *(u32*)(vrow + d * 168) = oo;
            }
        }
    }
    if (tid < 128) {
        *(uint4*)(Vt + (tid >> 1) * 168 + 144 + (tid & 1) * 8) = uint4{0, 0, 0, 0};
    }
    if (lane < 32) {
        *(uint4*)(Pb + wv * 16 * 168 + (lane >> 1) * 168 + 144 + (lane & 1) * 8) = uint4{0, 0, 0, 0};
    }
    __syncthreads();

    const int head = h * QMULT + wv;
    const int fr = lane & 15, fk = (lane >> 4) * 8;
    const int cr = (lane >> 4) * 4;
    u16* const Pw = Pb + wv * 16 * 168;

    const u16* qrow = qr + (long)(t0 + fr) * QD + head * HD;
    bf16x8 qf0 = *(const bf16x8*)(qrow + fk);
    bf16x8 qf1 = *(const bf16x8*)(qrow + 32 + fk);

    const int kmin = 128 - t0;
    float lsum[4] = {0.f, 0.f, 0.f, 0.f};

    for (int nt = 0; nt < 9; ++nt) {
        bf16x8 b0 = *(const bf16x8*)(ks + (nt * 16 + fr) * 72 + fk);
        bf16x8 b1 = *(const bf16x8*)(ks + (nt * 16 + fr) * 72 + 32 + fk);
        f32x4 s = f32x4{0.f, 0.f, 0.f, 0.f};
        s = __builtin_amdgcn_mfma_f32_16x16x32_bf16(qf0, b0, s, 0, 0, 0);
        s = __builtin_amdgcn_mfma_f32_16x16x32_bf16(qf1, b1, s, 0, 0, 0);
        const int kk = nt * 16 + fr;
        #pragma unroll
        for (int r = 0; r < 4; ++r) {
            int row = cr + r;
            bool valid = (kk >= row) && (kk <= row + 128) && (kk >= kmin);
            float p = valid ? __expf(s[r] * 0.125f) : 0.0f;
            lsum[r] += p;
            Pw[row * 168 + kk] = f2bf(p);
        }
    }

    f32x4 oacc[4];
    #pragma unroll
    for (int dt = 0; dt < 4; ++dt) oacc[dt] = f32x4{0.f, 0.f, 0.f, 0.f};
    #pragma unroll
    for (int k5 = 0; k5 < 5; ++k5) {
        const int k0 = k5 * 32;
        bf16x8 pa = *(const bf16x8*)(Pw + fr * 168 + k0 + fk);
        #pragma unroll
        for (int dt = 0; dt < 4; ++dt) {
            bf16x8 vf = *(const bf16x8*)(Vt + (dt * 16 + fr) * 168 + k0 + fk);
            oacc[dt] = __builtin_amdgcn_mfma_f32_16x16x32_bf16(pa, vf, oacc[dt], 0, 0, 0);
        }
    }

    #pragma unroll
    for (int r = 0; r < 4; ++r) {
        float v = lsum[r];
        v += __shfl_xor(v, 1);
        v += __shfl_xor(v, 2);
        v += __shfl_xor(v, 4);
        v += __shfl_xor(v, 8);
        lsum[r] = v;
    }
    const float sk = exp2f(sinks[head]);
    float inv[4];
    #pragma unroll
    for (int r = 0; r < 4; ++r) inv[r] = 1.0f / (lsum[r] + sk);

    #pragma unroll
    for (int dt = 0; dt < 4; ++dt) {
        #pragma unroll
        for (int r = 0; r < 4; ++r) {
            o[(long)(t0 + cr + r) * QD + head * HD + dt * 16 + fr] = f2bf(oacc[dt][r] * inv[r]);
        }
    }
}

// ---------------- reduce GEMM2 partials + bias + residual -> out ----------------
__global__ __launch_bounds__(256) void reduce2_kernel(const u16* __restrict__ p2a,
                                                      const u16* __restrict__ p2b,
                                                      const float* __restrict__ x,
                                                      const float* __restrict__ b_out,
                                                      float* __restrict__ out) {
    const int row = blockIdx.y;
    const int c4 = blockIdx.x * 256 + threadIdx.x;   // float4 index within row
    if (c4 >= 720) return;
    const int col = c4 * 4;
    ushort4 ua = *(const ushort4*)(p2a + (long)row * NPAD + col);
    ushort4 ub = *(const ushort4*)(p2b + (long)row * NPAD + col);
    float4 xv = *(const float4*)(x + (long)row * HIDDEN + col);
    float4 bv = *(const float4*)(b_out + col);
    float4 o;
    o.x = xv.x + bv.x + __uint_as_float((u32)ua.x << 16) + __uint_as_float((u32)ub.x << 16);
    o.y = xv.y + bv.y + __uint_as_float((u32)ua.y << 16) + __uint_as_float((u32)ub.y << 16);
    o.z = xv.z + bv.z + __uint_as_float((u32)ua.z << 16) + __uint_as_float((u32)ub.z << 16);
    o.w = xv.w + bv.w + __uint_as_float((u32)ua.w << 16) + __uint_as_float((u32)ub.w << 16);
    *(float4*)(out + (long)row * HIDDEN + col) = o;
}

// ---------------- launcher ----------------
extern "C" void kernel_launch(void* const* d_in, const int* in_sizes, int n_in,
                              void* d_out, int out_size, void* d_ws, size_t ws_size,
                              hipStream_t stream) {
    const float* x      = (const float*)d_in[0];
    const float* nscale = (const float*)d_in[1];
    const float* w_qkv  = (const float*)d_in[2];
    const float* b_qkv  = (const float*)d_in[3];
    const float* sinks  = (const float*)d_in[4];
    const float* w_out  = (const float*)d_in[5];
    const float* b_out  = (const float*)d_in[6];
    float* out = (float*)d_out;

    static int smem_set = 0;
    if (!smem_set) {
        hipFuncSetAttribute((const void*)gemm_bt_8ph,
                            hipFuncAttributeMaxDynamicSharedMemorySize, 131072);
        hipFuncSetAttribute((const void*)gemm_bt_3q,
                            hipFuncAttributeMaxDynamicSharedMemorySize, 114688);
        hipFuncSetAttribute((const void*)attn_kernel,
                            hipFuncAttributeMaxDynamicSharedMemorySize, 85248);
        smem_set = 1;
    }

    char* ws = (char*)d_ws;
    size_t off = 0;
    auto alloc = [&](size_t bytes) { void* p = ws + off; off += (bytes + 255) & ~(size_t)255; return p; };
    const size_t p1_bytes  = (size_t)TTOK * QKVD * 2;          // 21.0 MB (GEMM1 out)
    const size_t p2_bytes  = (size_t)2 * TTOK * NPAD * 2;      // 25.2 MB (GEMM2 partials)
    u16* wqkv_bf = (u16*)alloc((size_t)QKVD * HIDDEN * 2);     // 29.5 MB
    u16* wout_bf = (u16*)alloc((size_t)NPAD * QD * 2);         // 25.2 MB
    u16* h       = (u16*)alloc((size_t)TTOK * HIDDEN * 2);     // 11.8 MB
    u16* p1      = (u16*)alloc(p1_bytes > p2_bytes ? p1_bytes : p2_bytes);
    u16* qrot    = (u16*)alloc((size_t)TTOK * QD * 2);         // 16.8 MB
    // aliases (dead-after analysis):
    u16* attn = wqkv_bf;                       // wqkv_bf dead after gemm1 (16.8 MB)
    u16* krot = wqkv_bf + (size_t)TTOK * QD;   // wqkv tail: +2.1 MB
    u16* vrot = krot + (size_t)NKV * TTOK * HD;// +2.1 MB (total 21.0 <= 29.5 OK)
    u16* p2   = p1;                            // p1 dead after rope; sized above

    prep_kernel<<<PREP_QKV_BLOCKS + PREP_RMS_BLOCKS, 256, 0, stream>>>(
        w_qkv, wqkv_bf, x, nscale, h);
    // GEMM1: full-K, 160 gemm blocks + 96 working filler blocks (z=1; rest exit)
    gemm_bt_8ph<<<dim3(QKVD / 256, TTOK / 256, 2), 512, 131072, stream>>>(
        h, wqkv_bf, p1, QKVD, HIDDEN, HIDDEN, QKVD - 1, QKVD, 1, 96, w_out, wout_bf);
    rope_kernel<<<TTOK, 256, 0, stream>>>(p1, b_qkv, qrot, krot, vrot, 1);
    // attn: merged-z, 128x8 = 1024 blocks x 512 thr, 85 KB dynamic LDS
    attn_kernel<<<dim3(TTOK / 16, NKV), 512, 85248, stream>>>(
        qrot, krot, vrot, sinks, attn);
    // GEMM2: 256x192 tiles, split-K z=2 -> 16x8x2 = 256 blocks (FULL fill)
    gemm_bt_3q<<<dim3(NPAD / 192, TTOK / 256, 2), 512, 114688, stream>>>(
        attn, wout_bf, p2, NPAD, QD, QD / 2, NPAD - 1);
    reduce2_kernel<<<dim3(3, TTOK), 256, 0, stream>>>(
        p2, p2 + (size_t)TTOK * NPAD, x, b_out, out);
}